// Round 6
// baseline (531.758 us; speedup 1.0000x reference)
//
#include <hip/hip_runtime.h>

#define BB 1024
#define TT 2048
#define NIN 8
#define NHI 64

#define CS 2.8853900817779268f      /* 2*log2(e) */
#define ICS (1.0f / CS)
#define NL2E 1.4426950408889634f    /* log2(e) */
#define DELTA (40.94f / 2047.0f)

// exact sigmoid on prescaled arg: zs = -log2e*z -> 1/(1+exp2(zs))
__device__ __forceinline__ float sig_pre(float zs) {
    float e = __builtin_amdgcn_exp2f(zs);
    return __builtin_amdgcn_rcpf(1.0f + e);
}

// LDS lerp table sigma(v) = 1/(1+2^v), v in [-16,16], 1024 intervals (step 1/32)
#define STAB_N 1025
__device__ __forceinline__ float tab_sig(const float* stab, float zs) {
    float t = fmaf(zs, 32.0f, 512.0f);
    t = fminf(fmaxf(t, 0.0f), 1023.99f);
    int i = (int)t;
    float fr = t - (float)i;
    float a = stab[i];
    float b = stab[i + 1];
    return fmaf(fr, b - a, a);
}

template<int CTRL>
__device__ __forceinline__ float qperm(float x) {
    int r = __builtin_amdgcn_mov_dpp(__float_as_int(x), CTRL, 0xF, 0xF, true);
    return __int_as_float(r);
}

// ---------------- precompute g = h*r records [b][s][{gg,ga,gc}] -------------
__global__ __launch_bounds__(256) void precompute_r(
    const float* __restrict__ u, const float* __restrict__ Wni,
    const float* __restrict__ bni, const float* __restrict__ Wli,
    const float* __restrict__ bli, const float* __restrict__ tau,
    float* __restrict__ r3)
{
    __shared__ float sWni[NHI * NIN];
    __shared__ float sbni[NHI];
    __shared__ float sWli[NHI];
    __shared__ float stab[STAB_N];
    int lt = threadIdx.x;
    for (int i = lt; i < NHI * NIN; i += 256) sWni[i] = Wni[i] * -NL2E;
    if (lt < NHI) { sbni[lt] = bni[lt] * -NL2E; sWli[lt] = Wli[lt]; }
    for (int k = lt; k < STAB_N; k += 256) {
        float v = fmaf((float)k, 1.0f / 32.0f, -16.0f);
        stab[k] = sig_pre(v);
    }
    __syncthreads();

    int lane = lt & 63;
    long long gw = (long long)blockIdx.x * 4 + (lt >> 6);   // 1024*33 waves
    int b = (int)(gw / 33);
    int chunk = (int)(gw % 33);
    int s = chunk * 63 + lane;
    int sc = s < TT ? s : TT - 1;

    const float4* up4 = reinterpret_cast<const float4*>(u + ((long long)b * TT + sc) * NIN);
    float4 uA = up4[0], uB = up4[1];

    float d0 = 0.f, d1 = 0.f, d2 = 0.f;
    #pragma unroll 8
    for (int j = 0; j < NHI; j++) {
        const float* wj = &sWni[j * NIN];
        float z = sbni[j];
        z = fmaf(wj[0], uA.x, z); z = fmaf(wj[1], uA.y, z);
        z = fmaf(wj[2], uA.z, z); z = fmaf(wj[3], uA.w, z);
        z = fmaf(wj[4], uB.x, z); z = fmaf(wj[5], uB.y, z);
        z = fmaf(wj[6], uB.z, z); z = fmaf(wj[7], uB.w, z);
        float zn = __shfl_down(z, 1);
        float dz = zn - z;
        float z1 = fmaf(dz, 1.0f / 3.0f, z);
        float z2 = fmaf(dz, 2.0f / 3.0f, z);
        float wl = sWli[j];
        d0 = fmaf(wl, tab_sig(stab, z),  d0);
        d1 = fmaf(wl, tab_sig(stab, z1), d1);
        d2 = fmaf(wl, tab_sig(stab, z2), d2);
    }
    float base = tau[0] + bli[0];
    // store h*r (pre-scaled) so the scan needs no h multiplies
    float g0 = DELTA * __builtin_amdgcn_exp2f((base + d0) * -NL2E);
    float g1 = DELTA * __builtin_amdgcn_exp2f((base + d1) * -NL2E);
    float g2 = DELTA * __builtin_amdgcn_exp2f((base + d2) * -NL2E);

    if (s < TT) {
        float* p = r3 + ((long long)b * TT + s) * 3;
        p[0] = g0;
        if (lane < 63 && s < TT - 1) { p[1] = g1; p[2] = g2; }
    }
}

// ---------------- sequential RK4 scan: one b per quad, lane = component -----
// Scaled state X = CS*x. Records now hold g = h*r directly.
// Per-stage chain: exp2 -> add1 -> rcp -> dpp -> fma -> fma.
__global__ __launch_bounds__(64) void scan_kernel(
    const float* __restrict__ r3, float* __restrict__ xs)
{
    int gt = blockIdx.x * 64 + threadIdx.x;     // 4096 threads
    int b = gt >> 2;
    int l = gt & 3;

    const float4* rp = reinterpret_cast<const float4*>(r3 + (long long)b * TT * 3);
    int comp = (l == 3) ? 1 : l;
    float* xc = xs + (long long)comp * BB * TT + (long long)b * TT;

    bool is2 = (l == 2);
    float cA = is2 ? 40.0f * CS : -2.0f * CS;
    float cB = is2 ? -20.0f * CS : 0.0f;
    float Kl = is2 ? -10.0f * CS : CS;

    float X = (l == 0) ? 0.4736f * CS : (is2 ? 1.8497f * CS : 0.8745f * CS);

#define STEP(G1v, G2v, G3v, G4v) do { \
    float g1 = (G1v), g2 = (G2v), g3 = (G3v); \
    float q  = g1 * (1.0f / 3.0f); \
    float g4_8 = (G4v) * 0.125f; \
    float cA1 = q * cA,    cB1 = q * cB; \
    float cA2 = g2 * cA,   cB2 = g2 * cB; \
    float cA3 = g3 * cA,   cB3 = g3 * cB; \
    float cA4 = g4_8 * cA, cB4 = g4_8 * cB; \
    /* stage 1 */ \
    float e1 = __builtin_amdgcn_exp2f(X); \
    float rho1 = __builtin_amdgcn_rcpf(1.0f + e1); \
    float KmX = Kl - X; \
    float pb2 = fmaf(q, KmX, X); \
    float p11 = qperm<0x89>(rho1), p21 = qperm<0x10>(rho1); \
    float S2 = fmaf(cA1, p11, fmaf(cB1, p21, pb2)); \
    float V1 = fmaf(cA, p11, cB * p21); \
    float W1 = V1 + KmX; \
    /* stage 2 */ \
    float e2 = __builtin_amdgcn_exp2f(S2); \
    float rho2 = __builtin_amdgcn_rcpf(1.0f + e2); \
    float KmS2 = Kl - S2; \
    float pb3 = fmaf(g2, KmS2, fmaf(-q, W1, X)); \
    float p12 = qperm<0x89>(rho2), p22 = qperm<0x10>(rho2); \
    float S3 = fmaf(cA2, p12, fmaf(cB2, p22, pb3)); \
    float V2 = fmaf(cA, p12, cB * p22); \
    float W2 = V2 + KmS2; \
    /* stage 3 */ \
    float e3 = __builtin_amdgcn_exp2f(S3); \
    float rho3 = __builtin_amdgcn_rcpf(1.0f + e3); \
    float KmS3 = Kl - S3; \
    float pb4 = fmaf(g3, KmS3, fmaf(-g2, W2, fmaf(g1, W1, X))); \
    float p13 = qperm<0x89>(rho3), p23 = qperm<0x10>(rho3); \
    float S4 = fmaf(cA3, p13, fmaf(cB3, p23, pb4)); \
    float V3 = fmaf(cA, p13, cB * p23); \
    float W3 = V3 + KmS3; \
    /* stage 4 */ \
    float e4 = __builtin_amdgcn_exp2f(S4); \
    float rho4 = __builtin_amdgcn_rcpf(1.0f + e4); \
    float KmS4 = Kl - S4; \
    float t3 = fmaf(3.0f * g3, W3, fmaf(3.0f * g2, W2, g1 * W1)); \
    float pbX = fmaf(g4_8, KmS4, fmaf(0.125f, t3, X)); \
    float p14 = qperm<0x89>(rho4), p24 = qperm<0x10>(rho4); \
    X = fmaf(cA4, p14, fmaf(cB4, p24, pbX)); \
} while (0)

    float4 f0 = rp[0], f1 = rp[1], f2 = rp[2];
    float4 n0 = rp[3], n1 = rp[4], n2 = rp[5];

    for (int j = 0; j < 510; j++) {
        float4 m0 = rp[3 * j + 6], m1 = rp[3 * j + 7], m2 = rp[3 * j + 8];
        float4 ov;
        ov.x = X * ICS;
        STEP(f0.x, f0.y, f0.z, f0.w);  ov.y = X * ICS;
        STEP(f0.w, f1.x, f1.y, f1.z);  ov.z = X * ICS;
        STEP(f1.z, f1.w, f2.x, f2.y);  ov.w = X * ICS;
        *reinterpret_cast<float4*>(xc + 4 * j) = ov;
        STEP(f2.y, f2.z, f2.w, n0.x);
        f0 = n0; f1 = n1; f2 = n2;
        n0 = m0; n1 = m1; n2 = m2;
    }
    {   // chunk 510 (steps 2040..2043)
        float4 ov;
        ov.x = X * ICS;
        STEP(f0.x, f0.y, f0.z, f0.w);  ov.y = X * ICS;
        STEP(f0.w, f1.x, f1.y, f1.z);  ov.z = X * ICS;
        STEP(f1.z, f1.w, f2.x, f2.y);  ov.w = X * ICS;
        *reinterpret_cast<float4*>(xc + 4 * 510) = ov;
        STEP(f2.y, f2.z, f2.w, n0.x);
        f0 = n0; f1 = n1; f2 = n2;
    }
    {   // chunk 511 (steps 2044..2046 -> X(2045..2047))
        float4 ov;
        ov.x = X * ICS;
        STEP(f0.x, f0.y, f0.z, f0.w);  ov.y = X * ICS;
        STEP(f0.w, f1.x, f1.y, f1.z);  ov.z = X * ICS;
        STEP(f1.z, f1.w, f2.x, f2.y);  ov.w = X * ICS;
        *reinterpret_cast<float4*>(xc + 4 * 511) = ov;
    }
#undef STEP
}

// ---------------- readout: out = sigmoid(x @ Wn^T + bn) @ Wl^T + bl --------
__global__ __launch_bounds__(256) void out_kernel(
    const float* __restrict__ xs, const float* __restrict__ Wn,
    const float* __restrict__ bn, const float* __restrict__ Wl,
    const float* __restrict__ bl, float* __restrict__ out)
{
    __shared__ float sWn[NHI * 3];
    __shared__ float sbn[NHI];
    __shared__ float sWl[NHI];
    __shared__ float stab[STAB_N];
    int lt = threadIdx.x;
    if (lt < NHI * 3) sWn[lt] = Wn[lt] * -NL2E;
    if (lt < NHI) { sbn[lt] = bn[lt] * -NL2E; sWl[lt] = Wl[lt]; }
    for (int k = lt; k < STAB_N; k += 256) {
        float v = fmaf((float)k, 1.0f / 32.0f, -16.0f);
        stab[k] = sig_pre(v);
    }
    __syncthreads();

    long long tid = (long long)blockIdx.x * 256 + lt;   // tid = b*T + t
    float c0 = xs[tid];
    float c1 = xs[(long long)BB * TT + tid];
    float c2 = xs[(long long)2 * BB * TT + tid];
    float acc = 0.0f;
    #pragma unroll 8
    for (int j = 0; j < NHI; j++) {
        float z = fmaf(sWn[j * 3], c0,
                  fmaf(sWn[j * 3 + 1], c1,
                  fmaf(sWn[j * 3 + 2], c2, sbn[j])));
        acc = fmaf(sWl[j], tab_sig(stab, z), acc);
    }
    out[tid] = acc + bl[0];
}

extern "C" void kernel_launch(void* const* d_in, const int* in_sizes, int n_in,
                              void* d_out, int out_size, void* d_ws, size_t ws_size,
                              hipStream_t stream) {
    const float* u    = (const float*)d_in[0];
    const float* Wni  = (const float*)d_in[1];
    const float* bni  = (const float*)d_in[2];
    const float* Wli  = (const float*)d_in[3];
    const float* bli  = (const float*)d_in[4];
    const float* tau  = (const float*)d_in[5];
    const float* Wn   = (const float*)d_in[6];
    const float* bn   = (const float*)d_in[7];
    const float* Wl   = (const float*)d_in[8];
    const float* bl   = (const float*)d_in[9];
    float* out = (float*)d_out;

    float* r3 = (float*)d_ws;                          // B*T*3 floats (24 MB)
    float* xs = r3 + (size_t)3 * BB * TT;              // [3][B][T] (24 MB)

    precompute_r<<<(BB * 33) / 4, 256, 0, stream>>>(u, Wni, bni, Wli, bli, tau, r3);
    scan_kernel<<<(BB * 4) / 64, 64, 0, stream>>>(r3, xs);
    out_kernel<<<(BB * TT) / 256, 256, 0, stream>>>(xs, Wn, bn, Wl, bl, out);
}